// Round 3
// baseline (533.448 us; speedup 1.0000x reference)
//
#include <hip/hip_runtime.h>
#include <cstdint>

#define B_  8
#define N_  2048
#define M_  2048
#define C_  768
#define H_  12
#define P_  4
#define Dh_ 64

typedef float  f32x4  __attribute__((ext_vector_type(4)));
typedef __bf16 bf16x8 __attribute__((ext_vector_type(8)));
typedef unsigned short u16;
typedef unsigned short u16x8 __attribute__((ext_vector_type(8)));

__device__ __forceinline__ float bf2f(u16 u) {
  unsigned int x = ((unsigned int)u) << 16;
  return __builtin_bit_cast(float, x);
}
__device__ __forceinline__ u16 f2bf(float f) {
  unsigned int x = __builtin_bit_cast(unsigned int, f);
  x += 0x7fffu + ((x >> 16) & 1u);
  return (u16)(x >> 16);
}

// ---------------- 768x768 transpose + convert: WT[n][k] = W[k][n] ----------------
__global__ __launch_bounds__(256) void transpose_conv(const float* __restrict__ Win,
                                                      u16* __restrict__ WT) {
  __shared__ float t[32][33];
  int bx = blockIdx.x % 24, by = blockIdx.x / 24;
  int tx = threadIdx.x % 32, ty = threadIdx.x / 32;  // ty in 0..7
#pragma unroll
  for (int j = 0; j < 4; j++) {
    int row = ty + j * 8;
    t[row][tx] = Win[(size_t)(by * 32 + row) * C_ + bx * 32 + tx];
  }
  __syncthreads();
#pragma unroll
  for (int j = 0; j < 4; j++) {
    int row = ty + j * 8;
    WT[(size_t)(bx * 32 + row) * C_ + by * 32 + tx] = f2bf(t[tx][row]);
  }
}

// ---------------- bf16 GEMM with fused f32->bf16 A conversion ----------------
// C[Mr,Nc] = A_f32[Mr,K] * BT_bf16[Nc,K]^T
// 128x128 tile, BK=32, 4 waves (2x2), 16x16x32 MFMA, register-staged LDS.
__global__ __launch_bounds__(256) void gemm_af32(const float* __restrict__ Af,
                                                 const u16* __restrict__ BT,
                                                 u16* __restrict__ Cmat,
                                                 int Mr, int Nc, int K) {
  __shared__ __attribute__((aligned(16))) u16 Atile[128 * 32];
  __shared__ __attribute__((aligned(16))) u16 Btile[128 * 32];
  const int nbn = Nc >> 7;
  const int brow = blockIdx.x / nbn, bcol = blockIdx.x % nbn;
  const int tid = threadIdx.x;
  const int w = tid >> 6, lane = tid & 63;
  const int wm = (w >> 1) << 6, wn = (w & 1) << 6;
  const int lr = lane & 15, lk = (lane >> 4) << 3;

  f32x4 acc[4][4];
#pragma unroll
  for (int i = 0; i < 4; i++)
#pragma unroll
    for (int j = 0; j < 4; j++) acc[i][j] = (f32x4){0.f, 0.f, 0.f, 0.f};

  const int o1 = tid * 16;                      // byte offset in 8KB LDS tile
  const int o2 = o1 + 4096;
  const int r1 = o1 >> 6, c1 = (o1 & 63) >> 1;  // row / element-col (8-elem group)
  const int r2 = o2 >> 6, c2 = (o2 & 63) >> 1;
  const float* Ab = Af + (size_t)(brow * 128) * K;
  const u16*   Bb = BT + (size_t)(bcol * 128) * K;

  for (int kt = 0; kt < K; kt += 32) {
    // global loads (f32 A rows, bf16 B rows) into registers
    const float* pa1 = Ab + (size_t)r1 * K + kt + c1;
    const float* pa2 = Ab + (size_t)r2 * K + kt + c2;
    float4 a10 = *(const float4*)pa1;
    float4 a11 = *(const float4*)(pa1 + 4);
    float4 a20 = *(const float4*)pa2;
    float4 a21 = *(const float4*)(pa2 + 4);
    u16x8 b1 = *(const u16x8*)(Bb + (size_t)r1 * K + kt + c1);
    u16x8 b2 = *(const u16x8*)(Bb + (size_t)r2 * K + kt + c2);
    u16x8 pA1, pA2;
    pA1[0] = f2bf(a10.x); pA1[1] = f2bf(a10.y); pA1[2] = f2bf(a10.z); pA1[3] = f2bf(a10.w);
    pA1[4] = f2bf(a11.x); pA1[5] = f2bf(a11.y); pA1[6] = f2bf(a11.z); pA1[7] = f2bf(a11.w);
    pA2[0] = f2bf(a20.x); pA2[1] = f2bf(a20.y); pA2[2] = f2bf(a20.z); pA2[3] = f2bf(a20.w);
    pA2[4] = f2bf(a21.x); pA2[5] = f2bf(a21.y); pA2[6] = f2bf(a21.z); pA2[7] = f2bf(a21.w);

    __syncthreads();  // previous tile fully consumed
    *(u16x8*)((char*)Atile + o1) = pA1;
    *(u16x8*)((char*)Atile + o2) = pA2;
    *(u16x8*)((char*)Btile + o1) = b1;
    *(u16x8*)((char*)Btile + o2) = b2;
    __syncthreads();  // tile visible to all waves

    bf16x8 af[4], bfr[4];
#pragma unroll
    for (int mi = 0; mi < 4; mi++)
      af[mi] = *(const bf16x8*)&Atile[(wm + mi * 16 + lr) * 32 + lk];
#pragma unroll
    for (int ni = 0; ni < 4; ni++)
      bfr[ni] = *(const bf16x8*)&Btile[(wn + ni * 16 + lr) * 32 + lk];
#pragma unroll
    for (int mi = 0; mi < 4; mi++)
#pragma unroll
      for (int ni = 0; ni < 4; ni++)
        acc[mi][ni] = __builtin_amdgcn_mfma_f32_16x16x32_bf16(af[mi], bfr[ni], acc[mi][ni], 0, 0, 0);
  }
  // C/D layout (m89-verified): col = lane&15, row = (lane>>4)*4 + reg
  const int crow = brow * 128 + wm + ((lane >> 4) << 2);
  const int ccol = bcol * 128 + wn + lr;
#pragma unroll
  for (int mi = 0; mi < 4; mi++)
#pragma unroll
    for (int ni = 0; ni < 4; ni++)
#pragma unroll
      for (int r = 0; r < 4; r++)
        Cmat[(size_t)(crow + mi * 16 + r) * Nc + ccol + ni * 16] = f2bf(acc[mi][ni][r]);
}

// ---------------- column sums of v: vsr[b,c] = sum_m v[b,m,c] ----------------
__global__ __launch_bounds__(256) void vcolsum(const float* __restrict__ v,
                                               float* __restrict__ vsr) {
  int bid = blockIdx.x;  // b*48 + cc*16 + mc
  int b = bid / 48, rem = bid % 48, cc = rem / 16, mc = rem % 16;
  int c = cc * 256 + threadIdx.x;
  float s = 0.f;
  size_t base = ((size_t)b * M_ + mc * 128) * C_ + c;
  for (int m = 0; m < 128; m++) s += v[base + (size_t)m * C_];
  atomicAdd(&vsr[b * C_ + c], s);
}

// ---------------- vsum[b,hd] = vsr[b,:] @ vW[:,hd] ----------------
__global__ __launch_bounds__(256) void vsum_k(const float* __restrict__ vsr,
                                              const float* __restrict__ vW,
                                              float* __restrict__ vsum) {
  int b = blockIdx.x;
  __shared__ float vr[C_];
  for (int j = threadIdx.x; j < C_; j += 256) vr[j] = vsr[b * C_ + j];
  __syncthreads();
  int t = threadIdx.x;
  float s0 = 0.f, s1 = 0.f, s2 = 0.f;
  for (int c = 0; c < C_; c++) {
    float vc = vr[c];
    s0 += vc * vW[(size_t)c * C_ + t];
    s1 += vc * vW[(size_t)c * C_ + t + 256];
    s2 += vc * vW[(size_t)c * C_ + t + 512];
  }
  vsum[b * C_ + t] = s0;
  vsum[b * C_ + t + 256] = s1;
  vsum[b * C_ + t + 512] = s2;
}

// ---------------- W2[b,h,c] = sum_d vsum[b,h*64+d] * projW[h*64+d,c] ----------------
__global__ __launch_bounds__(256) void w2_k(const float* __restrict__ vsum,
                                            const float* __restrict__ projW,
                                            float* __restrict__ W2) {
  int bh = blockIdx.x;
  int b = bh / H_, h = bh % H_;
  __shared__ float vs[64];
  if (threadIdx.x < 64) vs[threadIdx.x] = vsum[b * C_ + h * 64 + threadIdx.x];
  __syncthreads();
#pragma unroll
  for (int j = 0; j < 3; j++) {
    int c = threadIdx.x + j * 256;
    float s = 0.f;
#pragma unroll 8
    for (int d = 0; d < 64; d++) s += vs[d] * projW[(size_t)(h * 64 + d) * C_ + c];
    W2[(size_t)bh * C_ + c] = s;
  }
}

// ---------------- off[row,p] = q[row,:] @ offW[:,2p] + offb[2p] ----------------
__global__ __launch_bounds__(256) void off_k(const float* __restrict__ q,
                                             const float* __restrict__ offW,
                                             const float* __restrict__ offb,
                                             float* __restrict__ offo) {
  int w = threadIdx.x >> 6, lane = threadIdx.x & 63;
  int row = blockIdx.x * 4 + w;
  float s0 = 0.f, s1 = 0.f, s2 = 0.f, s3 = 0.f;
  size_t base = (size_t)row * C_;
  for (int c = lane; c < C_; c += 64) {
    float qv = q[base + c];
    s0 += qv * offW[c * 8 + 0];
    s1 += qv * offW[c * 8 + 2];
    s2 += qv * offW[c * 8 + 4];
    s3 += qv * offW[c * 8 + 6];
  }
#pragma unroll
  for (int o = 32; o; o >>= 1) {
    s0 += __shfl_xor(s0, o, 64);
    s1 += __shfl_xor(s1, o, 64);
    s2 += __shfl_xor(s2, o, 64);
    s3 += __shfl_xor(s3, o, 64);
  }
  if (lane == 0) {
    offo[(size_t)row * 4 + 0] = s0 + offb[0];
    offo[(size_t)row * 4 + 1] = s1 + offb[2];
    offo[(size_t)row * 4 + 2] = s2 + offb[4];
    offo[(size_t)row * 4 + 3] = s3 + offb[6];
  }
}

// ---------------- logits[b,h,n] = scale * sum_d qp[b,n,h*64+d] * okv(n',d) ----------------
// okv(n',d) = (1/P) sum_p bilinear-sample of kp[b, d*32 + m>>6, h*64 + m&63] at x=off[b,n',p]
__global__ __launch_bounds__(256) void logits_k(const u16* __restrict__ qp,
                                                const u16* __restrict__ kp,
                                                const float* __restrict__ offo,
                                                float* __restrict__ logits) {
  int bid = blockIdx.x;
  int nc = bid & 3;
  int bh = bid >> 2;
  int h = bh % H_, b = bh / H_;
  int n0 = nc << 9;  // 512 n per block
  int npLo = (h * N_ + n0) / H_;
  int npHi = (h * N_ + n0 + 511) / H_;
  int cnt = npHi - npLo + 1;  // <= 44
  __shared__ float okv[45][64];
  int w = threadIdx.x >> 6, lane = threadIdx.x & 63;

  // phase 1: sampled vectors, one n' per wave-iteration, lane = d
  size_t kbase = ((size_t)b * M_ + (size_t)lane * 32) * C_ + h * 64;
  for (int idx = w; idx < cnt; idx += 4) {
    int np = npLo + idx;
    const float* op = &offo[((size_t)b * N_ + np) * 4];
    float accv = 0.f;
#pragma unroll
    for (int p = 0; p < P_; p++) {
      float x = op[p];
      float xf = floorf(x);
      float wf = x - xf;
      int x0 = (int)xf;
      int x1 = x0 + 1;
      int m0 = min(max(x0, 0), M_ - 1);
      int m1 = min(max(x1, 0), M_ - 1);
      float g0 = bf2f(kp[kbase + (size_t)(m0 >> 6) * C_ + (m0 & 63)]);
      float g1 = bf2f(kp[kbase + (size_t)(m1 >> 6) * C_ + (m1 & 63)]);
      float w0 = (x0 >= 0 && x0 < M_) ? (1.f - wf) : 0.f;
      float w1 = (x1 >= 0 && x1 < M_) ? wf : 0.f;
      accv += w0 * g0 + w1 * g1;
    }
    okv[idx][lane] = accv * 0.25f;
  }
  __syncthreads();

  // phase 2: 64-length dots, lane = d, each wave 128 consecutive n
  for (int i = 0; i < 128; i++) {
    int n = n0 + w * 128 + i;
    float qv = bf2f(qp[((size_t)b * N_ + n) * C_ + h * 64 + lane]);
    int idx = (h * N_ + n) / H_ - npLo;
    float prod = qv * okv[idx][lane];
#pragma unroll
    for (int o = 32; o; o >>= 1) prod += __shfl_xor(prod, o, 64);
    if (lane == 0) logits[(size_t)bh * N_ + n] = prod * 0.125f;
  }
}

// ---------------- softmax over n per (b,h) ----------------
__global__ __launch_bounds__(256) void softmax_k(const float* __restrict__ logits,
                                                 float* __restrict__ attn) {
  int bh = blockIdx.x;
  const float* L = logits + (size_t)bh * N_;
  float* O = attn + (size_t)bh * N_;
  int t = threadIdx.x, w = t >> 6, lane = t & 63;
  float v[8];
  float mx = -1e30f;
#pragma unroll
  for (int i = 0; i < 8; i++) {
    v[i] = L[t + i * 256];
    mx = fmaxf(mx, v[i]);
  }
#pragma unroll
  for (int o = 32; o; o >>= 1) mx = fmaxf(mx, __shfl_xor(mx, o, 64));
  __shared__ float sm[4], ss[4];
  if (lane == 0) sm[w] = mx;
  __syncthreads();
  mx = fmaxf(fmaxf(sm[0], sm[1]), fmaxf(sm[2], sm[3]));
  float s = 0.f;
#pragma unroll
  for (int i = 0; i < 8; i++) {
    v[i] = expf(v[i] - mx);
    s += v[i];
  }
#pragma unroll
  for (int o = 32; o; o >>= 1) s += __shfl_xor(s, o, 64);
  if (lane == 0) ss[w] = s;
  __syncthreads();
  s = ss[0] + ss[1] + ss[2] + ss[3];
  float inv = 1.f / s;
#pragma unroll
  for (int i = 0; i < 8; i++) O[t + i * 256] = v[i] * inv;
}

// ---------------- out[b,n,c] = sum_h attn[b,h,n]*W2[b,h,c] + projb[c] ----------------
__global__ __launch_bounds__(256) void out_k(const float* __restrict__ attn,
                                             const float* __restrict__ W2,
                                             const float* __restrict__ projb,
                                             float* __restrict__ out) {
  int bid = blockIdx.x;  // b*64 + nb
  int b = bid >> 6, nb = bid & 63;
  int n0 = nb << 5;
  __shared__ float at[32][12];
  __shared__ float w2s[12][C_];
  int t = threadIdx.x;
  // FIX (round 2 bug): 384 entries, 256 threads -> must stride, not `if (t<384)`.
  // Rows 21..31 of `at` were previously uninitialized LDS garbage -> absmax 92.5.
  for (int j = t; j < 32 * 12; j += 256) {
    int ni = j / 12, hh = j % 12;
    at[ni][hh] = attn[((size_t)(b * H_ + hh)) * N_ + n0 + ni];
  }
  for (int j = t; j < H_ * C_; j += 256) w2s[j / C_][j % C_] = W2[(size_t)b * H_ * C_ + j];
  __syncthreads();
#pragma unroll
  for (int ci = 0; ci < 3; ci++) {
    int c = t + ci * 256;
    float pb = projb[c];
    for (int ni = 0; ni < 32; ni++) {
      float s = pb;
#pragma unroll
      for (int hh = 0; hh < 12; hh++) s += at[ni][hh] * w2s[hh][c];
      out[((size_t)b * N_ + n0 + ni) * C_ + c] = s;
    }
  }
}

extern "C" void kernel_launch(void* const* d_in, const int* in_sizes, int n_in,
                              void* d_out, int out_size, void* d_ws, size_t ws_size,
                              hipStream_t stream) {
  const float* q     = (const float*)d_in[0];
  const float* k     = (const float*)d_in[1];
  const float* v     = (const float*)d_in[2];
  const float* qW    = (const float*)d_in[3];
  const float* kW    = (const float*)d_in[4];
  const float* vW    = (const float*)d_in[5];
  const float* offW  = (const float*)d_in[6];
  const float* offb  = (const float*)d_in[7];
  const float* projW = (const float*)d_in[8];
  const float* projb = (const float*)d_in[9];
  float* out = (float*)d_out;
  char* ws = (char*)d_ws;

  // workspace layout (bytes), total ~52.3 MB
  u16*   qWT    = (u16*)(ws);                    // 1179648
  u16*   kWT    = (u16*)(ws + 1179648);          // 1179648
  u16*   qp     = (u16*)(ws + 2359296);          // 25165824
  u16*   kp     = (u16*)(ws + 27525120);         // 25165824
  float* offo   = (float*)(ws + 52690944);       // 262144
  float* vsr    = (float*)(ws + 52953088);       // 24576
  float* vsum   = (float*)(ws + 52977664);       // 24576
  float* W2     = (float*)(ws + 53002240);       // 294912
  float* logits = (float*)(ws + 53297152);       // 786432
  float* attn   = (float*)(ws + 54083584);       // 786432

  hipMemsetAsync(vsr, 0, B_ * C_ * sizeof(float), stream);

  transpose_conv<<<576, 256, 0, stream>>>(qW, qWT);
  transpose_conv<<<576, 256, 0, stream>>>(kW, kWT);
  gemm_af32<<<768, 256, 0, stream>>>(q, qWT, qp, B_ * N_, C_, C_);
  gemm_af32<<<768, 256, 0, stream>>>(k, kWT, kp, B_ * M_, C_, C_);
  vcolsum<<<384, 256, 0, stream>>>(v, vsr);
  vsum_k<<<8, 256, 0, stream>>>(vsr, vW, vsum);
  w2_k<<<96, 256, 0, stream>>>(vsum, projW, W2);
  off_k<<<4096, 256, 0, stream>>>(q, offW, offb, offo);
  logits_k<<<384, 256, 0, stream>>>(qp, kp, offo, logits);
  softmax_k<<<96, 256, 0, stream>>>(logits, attn);
  out_k<<<512, 256, 0, stream>>>(attn, W2, projb, out);
}

// Round 4
// 355.386 us; speedup vs baseline: 1.5010x; 1.5010x over previous
//
#include <hip/hip_runtime.h>
#include <cstdint>

#define B_  8
#define N_  2048
#define M_  2048
#define C_  768
#define H_  12
#define P_  4
#define Dh_ 64

typedef float  f32x4  __attribute__((ext_vector_type(4)));
typedef __bf16 bf16x8 __attribute__((ext_vector_type(8)));
typedef unsigned short u16;
typedef unsigned short u16x8 __attribute__((ext_vector_type(8)));

__device__ __forceinline__ float bf2f(u16 u) {
  unsigned int x = ((unsigned int)u) << 16;
  return __builtin_bit_cast(float, x);
}
__device__ __forceinline__ u16 f2bf(float f) {
  unsigned int x = __builtin_bit_cast(unsigned int, f);
  x += 0x7fffu + ((x >> 16) & 1u);
  return (u16)(x >> 16);
}

// ---------------- 768x768 transpose + convert: WT[n][k] = W[k][n] ----------------
__global__ __launch_bounds__(256) void transpose_conv(const float* __restrict__ Win,
                                                      u16* __restrict__ WT) {
  __shared__ float t[32][33];
  int bx = blockIdx.x % 24, by = blockIdx.x / 24;
  int tx = threadIdx.x % 32, ty = threadIdx.x / 32;  // ty in 0..7
#pragma unroll
  for (int j = 0; j < 4; j++) {
    int row = ty + j * 8;
    t[row][tx] = Win[(size_t)(by * 32 + row) * C_ + bx * 32 + tx];
  }
  __syncthreads();
#pragma unroll
  for (int j = 0; j < 4; j++) {
    int row = ty + j * 8;
    WT[(size_t)(bx * 32 + row) * C_ + by * 32 + tx] = f2bf(t[tx][row]);
  }
}

// ---------------- bf16 GEMM with fused f32->bf16 A conversion ----------------
// C[Mr,Nc] = A_f32[Mr,K] * BT_bf16[Nc,K]^T
// 128x128 tile, BK=32, 4 waves (2x2), 16x16x32 MFMA, register-staged LDS.
__global__ __launch_bounds__(256) void gemm_af32(const float* __restrict__ Af,
                                                 const u16* __restrict__ BT,
                                                 u16* __restrict__ Cmat,
                                                 int Mr, int Nc, int K) {
  __shared__ __attribute__((aligned(16))) u16 Atile[128 * 32];
  __shared__ __attribute__((aligned(16))) u16 Btile[128 * 32];
  const int nbn = Nc >> 7;
  const int brow = blockIdx.x / nbn, bcol = blockIdx.x % nbn;
  const int tid = threadIdx.x;
  const int w = tid >> 6, lane = tid & 63;
  const int wm = (w >> 1) << 6, wn = (w & 1) << 6;
  const int lr = lane & 15, lk = (lane >> 4) << 3;

  f32x4 acc[4][4];
#pragma unroll
  for (int i = 0; i < 4; i++)
#pragma unroll
    for (int j = 0; j < 4; j++) acc[i][j] = (f32x4){0.f, 0.f, 0.f, 0.f};

  const int o1 = tid * 16;                      // byte offset in 8KB LDS tile
  const int o2 = o1 + 4096;
  const int r1 = o1 >> 6, c1 = (o1 & 63) >> 1;  // row / element-col (8-elem group)
  const int r2 = o2 >> 6, c2 = (o2 & 63) >> 1;
  const float* Ab = Af + (size_t)(brow * 128) * K;
  const u16*   Bb = BT + (size_t)(bcol * 128) * K;

  for (int kt = 0; kt < K; kt += 32) {
    const float* pa1 = Ab + (size_t)r1 * K + kt + c1;
    const float* pa2 = Ab + (size_t)r2 * K + kt + c2;
    float4 a10 = *(const float4*)pa1;
    float4 a11 = *(const float4*)(pa1 + 4);
    float4 a20 = *(const float4*)pa2;
    float4 a21 = *(const float4*)(pa2 + 4);
    u16x8 b1 = *(const u16x8*)(Bb + (size_t)r1 * K + kt + c1);
    u16x8 b2 = *(const u16x8*)(Bb + (size_t)r2 * K + kt + c2);
    u16x8 pA1, pA2;
    pA1[0] = f2bf(a10.x); pA1[1] = f2bf(a10.y); pA1[2] = f2bf(a10.z); pA1[3] = f2bf(a10.w);
    pA1[4] = f2bf(a11.x); pA1[5] = f2bf(a11.y); pA1[6] = f2bf(a11.z); pA1[7] = f2bf(a11.w);
    pA2[0] = f2bf(a20.x); pA2[1] = f2bf(a20.y); pA2[2] = f2bf(a20.z); pA2[3] = f2bf(a20.w);
    pA2[4] = f2bf(a21.x); pA2[5] = f2bf(a21.y); pA2[6] = f2bf(a21.z); pA2[7] = f2bf(a21.w);

    __syncthreads();
    *(u16x8*)((char*)Atile + o1) = pA1;
    *(u16x8*)((char*)Atile + o2) = pA2;
    *(u16x8*)((char*)Btile + o1) = b1;
    *(u16x8*)((char*)Btile + o2) = b2;
    __syncthreads();

    bf16x8 af[4], bfr[4];
#pragma unroll
    for (int mi = 0; mi < 4; mi++)
      af[mi] = *(const bf16x8*)&Atile[(wm + mi * 16 + lr) * 32 + lk];
#pragma unroll
    for (int ni = 0; ni < 4; ni++)
      bfr[ni] = *(const bf16x8*)&Btile[(wn + ni * 16 + lr) * 32 + lk];
#pragma unroll
    for (int mi = 0; mi < 4; mi++)
#pragma unroll
      for (int ni = 0; ni < 4; ni++)
        acc[mi][ni] = __builtin_amdgcn_mfma_f32_16x16x32_bf16(af[mi], bfr[ni], acc[mi][ni], 0, 0, 0);
  }
  const int crow = brow * 128 + wm + ((lane >> 4) << 2);
  const int ccol = bcol * 128 + wn + lr;
#pragma unroll
  for (int mi = 0; mi < 4; mi++)
#pragma unroll
    for (int ni = 0; ni < 4; ni++)
#pragma unroll
      for (int r = 0; r < 4; r++)
        Cmat[(size_t)(crow + mi * 16 + r) * Nc + ccol + ni * 16] = f2bf(acc[mi][ni][r]);
}

// ---------------- kp -> kpT[b][h][m][d] bit-mixed transpose ----------------
// kpT[((b*H+h)*M + m)*64 + d] = kp[(b*M + d*32 + (m>>6))*C + h*64 + (m&63)]
__global__ __launch_bounds__(256) void tkp_k(const u16* __restrict__ kp,
                                             u16* __restrict__ kpT) {
  int bid = blockIdx.x;        // ((b*12 + h)*32 + mb)
  int mb = bid & 31;
  int bh = bid >> 5;
  int h = bh % H_, b = bh / H_;
  __shared__ u16 tile[64][64];  // chunk-swizzled: row d, chunk ch stored at ch^(d>>3)
  int t = threadIdx.x;
#pragma unroll
  for (int rep = 0; rep < 2; rep++) {
    int idx = rep * 256 + t;
    int dp = idx >> 3, ch = idx & 7;
    u16x8 vv = *(const u16x8*)(kp + ((size_t)(b * M_ + dp * 32 + mb) * C_ + h * 64 + ch * 8));
    *(u16x8*)&tile[dp][(ch ^ (dp >> 3)) * 8] = vv;
  }
  __syncthreads();
#pragma unroll
  for (int rep = 0; rep < 2; rep++) {
    int idx = rep * 256 + t;
    int ml = idx >> 3, ch = idx & 7;   // output row m_lo, d-chunk ch
    int col = ((ml >> 3) ^ ch) * 8 + (ml & 7);  // swizzle key of row (ch*8+jj) is ch
    u16x8 o;
#pragma unroll
    for (int jj = 0; jj < 8; jj++) o[jj] = tile[ch * 8 + jj][col];
    *(u16x8*)(kpT + ((size_t)(bh * M_ + mb * 64 + ml) * 64 + ch * 8)) = o;
  }
}

// ---------------- column sums of v: vsr[b,c] = sum_m v[b,m,c] ----------------
__global__ __launch_bounds__(256) void vcolsum(const float* __restrict__ v,
                                               float* __restrict__ vsr) {
  int bid = blockIdx.x;  // b*48 + cc*16 + mc
  int b = bid / 48, rem = bid % 48, cc = rem / 16, mc = rem % 16;
  int c = cc * 256 + threadIdx.x;
  float s = 0.f;
  size_t base = ((size_t)b * M_ + mc * 128) * C_ + c;
  for (int m = 0; m < 128; m++) s += v[base + (size_t)m * C_];
  atomicAdd(&vsr[b * C_ + c], s);
}

// ---------------- vsum[b,c0+col] = vr[b,:] @ vW[:,c0+col], 192 blocks ----------------
__global__ __launch_bounds__(256) void vsum_k(const float* __restrict__ vsr,
                                              const float* __restrict__ vW,
                                              float* __restrict__ vsum) {
  int bid = blockIdx.x;  // b*24 + cc
  int b = bid / 24, cc = bid % 24;
  int c0 = cc * 32;
  __shared__ float vr[C_];
  __shared__ float part[8][32];
  int t = threadIdx.x;
  for (int j = t; j < C_; j += 256) vr[j] = vsr[b * C_ + j];
  __syncthreads();
  int col = t & 31, e = t >> 5;
  float s = 0.f;
  for (int c = e * 96; c < e * 96 + 96; c++) s += vr[c] * vW[(size_t)c * C_ + c0 + col];
  part[e][col] = s;
  __syncthreads();
  if (t < 32) {
    float acc = 0.f;
#pragma unroll
    for (int e2 = 0; e2 < 8; e2++) acc += part[e2][t];
    vsum[b * C_ + c0 + t] = acc;
  }
}

// ---------------- W2[b,h,c] = sum_d vsum[b,h*64+d] * projW[h*64+d,c] ----------------
__global__ __launch_bounds__(256) void w2_k(const float* __restrict__ vsum,
                                            const float* __restrict__ projW,
                                            float* __restrict__ W2) {
  int bh = blockIdx.x;
  int b = bh / H_, h = bh % H_;
  __shared__ float vs[64];
  if (threadIdx.x < 64) vs[threadIdx.x] = vsum[b * C_ + h * 64 + threadIdx.x];
  __syncthreads();
#pragma unroll
  for (int j = 0; j < 3; j++) {
    int c = threadIdx.x + j * 256;
    float s = 0.f;
#pragma unroll 8
    for (int d = 0; d < 64; d++) s += vs[d] * projW[(size_t)(h * 64 + d) * C_ + c];
    W2[(size_t)bh * C_ + c] = s;
  }
}

// ---------------- off_k v2: float4 q loads + LDS offW columns ----------------
__global__ __launch_bounds__(256) void off_k(const float* __restrict__ q,
                                             const float* __restrict__ offW,
                                             const float* __restrict__ offb,
                                             float* __restrict__ offo) {
  __shared__ __attribute__((aligned(16))) float ow0[C_], ow1[C_], ow2[C_], ow3[C_];
  int t = threadIdx.x, w = t >> 6, lane = t & 63;
  for (int j = t; j < C_; j += 256) {
    float4 lo = *(const float4*)(offW + j * 8);
    float4 hi = *(const float4*)(offW + j * 8 + 4);
    ow0[j] = lo.x; ow1[j] = lo.z; ow2[j] = hi.x; ow3[j] = hi.z;
  }
  __syncthreads();
  float b0 = offb[0], b1 = offb[2], b2 = offb[4], b3 = offb[6];
#pragma unroll
  for (int rr = 0; rr < 2; rr++) {
    int row = blockIdx.x * 8 + w * 2 + rr;
    const float* qr = q + (size_t)row * C_;
    float s0 = 0.f, s1 = 0.f, s2 = 0.f, s3 = 0.f;
#pragma unroll
    for (int it = 0; it < 3; it++) {
      int c = it * 256 + lane * 4;
      float4 qv = *(const float4*)(qr + c);
      f32x4 a0 = *(const f32x4*)&ow0[c];
      f32x4 a1 = *(const f32x4*)&ow1[c];
      f32x4 a2 = *(const f32x4*)&ow2[c];
      f32x4 a3 = *(const f32x4*)&ow3[c];
      s0 += qv.x * a0[0] + qv.y * a0[1] + qv.z * a0[2] + qv.w * a0[3];
      s1 += qv.x * a1[0] + qv.y * a1[1] + qv.z * a1[2] + qv.w * a1[3];
      s2 += qv.x * a2[0] + qv.y * a2[1] + qv.z * a2[2] + qv.w * a2[3];
      s3 += qv.x * a3[0] + qv.y * a3[1] + qv.z * a3[2] + qv.w * a3[3];
    }
#pragma unroll
    for (int o = 32; o; o >>= 1) {
      s0 += __shfl_xor(s0, o, 64);
      s1 += __shfl_xor(s1, o, 64);
      s2 += __shfl_xor(s2, o, 64);
      s3 += __shfl_xor(s3, o, 64);
    }
    if (lane == 0) {
      float4 ov = {s0 + b0, s1 + b1, s2 + b2, s3 + b3};
      *(float4*)(offo + (size_t)row * 4) = ov;
    }
  }
}

// ---------------- logits v2: coalesced kpT sampling + per-thread dot ----------------
__global__ __launch_bounds__(256) void logits_k(const u16* __restrict__ qp,
                                                const u16* __restrict__ kpT,
                                                const float* __restrict__ offo,
                                                float* __restrict__ logits) {
  int bid = blockIdx.x;      // (b*12+h)*8 + nc
  int nc = bid & 7;
  int bh = bid >> 3;
  int h = bh % H_, b = bh / H_;
  int n0 = nc << 8;          // 256 n per block
  int npLo = (h * N_ + n0) / H_;
  int npHi = (h * N_ + n0 + 255) / H_;
  int cnt = npHi - npLo + 1;  // <= 23
  __shared__ float okv[24][68];                    // padded: rows 272B, 16B-aligned
  __shared__ __attribute__((aligned(16))) u16 qtile[256][64];  // chunk ch at col ch^(row&7)
  int t = threadIdx.x, w = t >> 6, lane = t & 63;

  // stage q tile (coalesced, XOR-swizzled chunks)
#pragma unroll
  for (int rep = 0; rep < 8; rep++) {
    int row = rep * 32 + (t >> 3), ch = t & 7;
    u16x8 vv = *(const u16x8*)(qp + ((size_t)(b * N_ + n0 + row) * C_ + h * 64 + ch * 8));
    *(u16x8*)&qtile[row][(ch ^ (row & 7)) * 8] = vv;
  }

  // okv: coalesced 128B row reads from kpT, lane = d
  const u16* kb = kpT + (size_t)bh * M_ * 64;
  for (int idx = w; idx < cnt; idx += 4) {
    int np = npLo + idx;
    const float* op = &offo[((size_t)b * N_ + np) * 4];
    float accv = 0.f;
#pragma unroll
    for (int p = 0; p < P_; p++) {
      float x = op[p];
      float xf = floorf(x);
      float wf = x - xf;
      int x0 = (int)xf, x1 = x0 + 1;
      int m0 = min(max(x0, 0), M_ - 1);
      int m1 = min(max(x1, 0), M_ - 1);
      float g0 = bf2f(kb[(size_t)m0 * 64 + lane]);
      float g1 = bf2f(kb[(size_t)m1 * 64 + lane]);
      float w0 = (x0 >= 0 && x0 < M_) ? (1.f - wf) : 0.f;
      float w1 = (x1 >= 0 && x1 < M_) ? wf : 0.f;
      accv += w0 * g0 + w1 * g1;
    }
    okv[idx][lane] = accv * 0.25f;
  }
  __syncthreads();

  // per-thread 64-length dot (no shfl)
  int n = n0 + t;
  int idx = (h * N_ + n) / H_ - npLo;
  float s = 0.f;
#pragma unroll
  for (int j = 0; j < 8; j++) {
    u16x8 qv = *(const u16x8*)&qtile[t][(j ^ (t & 7)) * 8];
    const float* orow = &okv[idx][j * 8];
    f32x4 o0 = *(const f32x4*)(orow);
    f32x4 o1 = *(const f32x4*)(orow + 4);
    s += bf2f(qv[0]) * o0[0] + bf2f(qv[1]) * o0[1] + bf2f(qv[2]) * o0[2] + bf2f(qv[3]) * o0[3]
       + bf2f(qv[4]) * o1[0] + bf2f(qv[5]) * o1[1] + bf2f(qv[6]) * o1[2] + bf2f(qv[7]) * o1[3];
  }
  logits[(size_t)bh * N_ + n] = s * 0.125f;
}

// ---------------- softmax over n per (b,h) ----------------
__global__ __launch_bounds__(256) void softmax_k(const float* __restrict__ logits,
                                                 float* __restrict__ attn) {
  int bh = blockIdx.x;
  const float* L = logits + (size_t)bh * N_;
  float* O = attn + (size_t)bh * N_;
  int t = threadIdx.x, w = t >> 6, lane = t & 63;
  float v[8];
  float mx = -1e30f;
#pragma unroll
  for (int i = 0; i < 8; i++) {
    v[i] = L[t + i * 256];
    mx = fmaxf(mx, v[i]);
  }
#pragma unroll
  for (int o = 32; o; o >>= 1) mx = fmaxf(mx, __shfl_xor(mx, o, 64));
  __shared__ float sm[4], ss[4];
  if (lane == 0) sm[w] = mx;
  __syncthreads();
  mx = fmaxf(fmaxf(sm[0], sm[1]), fmaxf(sm[2], sm[3]));
  float s = 0.f;
#pragma unroll
  for (int i = 0; i < 8; i++) {
    v[i] = expf(v[i] - mx);
    s += v[i];
  }
#pragma unroll
  for (int o = 32; o; o >>= 1) s += __shfl_xor(s, o, 64);
  if (lane == 0) ss[w] = s;
  __syncthreads();
  s = ss[0] + ss[1] + ss[2] + ss[3];
  float inv = 1.f / s;
#pragma unroll
  for (int i = 0; i < 8; i++) O[t + i * 256] = v[i] * inv;
}

// ---------------- out[b,n,c] = sum_h attn[b,h,n]*W2[b,h,c] + projb[c] ----------------
__global__ __launch_bounds__(256) void out_k(const float* __restrict__ attn,
                                             const float* __restrict__ W2,
                                             const float* __restrict__ projb,
                                             float* __restrict__ out) {
  int bid = blockIdx.x;  // b*64 + nb
  int b = bid >> 6, nb = bid & 63;
  int n0 = nb << 5;
  __shared__ float at[32][12];
  __shared__ float w2s[12][C_];
  int t = threadIdx.x;
  for (int j = t; j < 32 * 12; j += 256) {
    int ni = j / 12, hh = j % 12;
    at[ni][hh] = attn[((size_t)(b * H_ + hh)) * N_ + n0 + ni];
  }
  for (int j = t; j < H_ * C_; j += 256) w2s[j / C_][j % C_] = W2[(size_t)b * H_ * C_ + j];
  __syncthreads();
#pragma unroll
  for (int ci = 0; ci < 3; ci++) {
    int c = t + ci * 256;
    float pb = projb[c];
    for (int ni = 0; ni < 32; ni++) {
      float s = pb;
#pragma unroll
      for (int hh = 0; hh < 12; hh++) s += at[ni][hh] * w2s[hh][c];
      out[((size_t)b * N_ + n0 + ni) * C_ + c] = s;
    }
  }
}

extern "C" void kernel_launch(void* const* d_in, const int* in_sizes, int n_in,
                              void* d_out, int out_size, void* d_ws, size_t ws_size,
                              hipStream_t stream) {
  const float* q     = (const float*)d_in[0];
  const float* k     = (const float*)d_in[1];
  const float* v     = (const float*)d_in[2];
  const float* qW    = (const float*)d_in[3];
  const float* kW    = (const float*)d_in[4];
  const float* vW    = (const float*)d_in[5];
  const float* offW  = (const float*)d_in[6];
  const float* offb  = (const float*)d_in[7];
  const float* projW = (const float*)d_in[8];
  const float* projb = (const float*)d_in[9];
  float* out = (float*)d_out;
  char* ws = (char*)d_ws;

  // workspace layout (bytes), total 80035840 (same as verified round-1 footprint)
  u16*   qWT    = (u16*)(ws);                    // 1179648
  u16*   kWT    = (u16*)(ws + 1179648);          // 1179648
  u16*   qp     = (u16*)(ws + 2359296);          // 25165824
  u16*   kp     = (u16*)(ws + 27525120);         // 25165824
  u16*   kpT    = (u16*)(ws + 52690944);         // 25165824
  float* offo   = (float*)(ws + 77856768);       // 262144
  float* vsr    = (float*)(ws + 78118912);       // 24576
  float* vsum   = (float*)(ws + 78143488);       // 24576
  float* W2     = (float*)(ws + 78168064);       // 294912
  float* logits = (float*)(ws + 78462976);       // 786432
  float* attn   = (float*)(ws + 79249408);       // 786432

  hipMemsetAsync(vsr, 0, B_ * C_ * sizeof(float), stream);

  transpose_conv<<<576, 256, 0, stream>>>(qW, qWT);
  transpose_conv<<<576, 256, 0, stream>>>(kW, kWT);
  gemm_af32<<<768, 256, 0, stream>>>(q, qWT, qp, B_ * N_, C_, C_);
  gemm_af32<<<768, 256, 0, stream>>>(k, kWT, kp, B_ * M_, C_, C_);
  tkp_k<<<3072, 256, 0, stream>>>(kp, kpT);
  vcolsum<<<384, 256, 0, stream>>>(v, vsr);
  vsum_k<<<192, 256, 0, stream>>>(vsr, vW, vsum);
  w2_k<<<96, 256, 0, stream>>>(vsum, projW, W2);
  off_k<<<2048, 256, 0, stream>>>(q, offW, offb, offo);
  logits_k<<<768, 256, 0, stream>>>(qp, kpT, offo, logits);
  softmax_k<<<96, 256, 0, stream>>>(logits, attn);
  out_k<<<512, 256, 0, stream>>>(attn, W2, projb, out);
}